// Round 7
// baseline (21405.458 us; speedup 1.0000x reference)
//
#include <hip/hip_runtime.h>
#include <cmath>

#define L_     10
#define R_     64
#define G_     128
#define S_     256
#define MEL_   80
#define NCLS_  256
#define HOP_   64
#define END_   256
#define FRAMES_ 8
#define T_     512

typedef unsigned long long u64;

// ---- workspace layout (float offsets; all mailbox offsets 8B-aligned) ----
#define COND8_OFF   0                                // 8*1280
#define HIST_OFF    10240                            // rows 0..7 = inputs of l1..l8: [row][512][64]
#define MBX5_OFF    (HIST_OFF + 8*T_*R_)             // u64 x5 mailbox [64] (A->B)
#define ZMB_OFF     (MBX5_OFF + 2*R_)                // u64 z mailboxes [10][64]
#define CTR64_OFF   (ZMB_OFF + 10*R_*2)              // u64 contribs [10][256] (0..6,8 used)
#define HID64_OFF   (CTR64_OFF + 10*S_*2)            // u64 C->D [256]
#define FLAG_OFF    (HID64_OFF + S_*2)               // flags, 16 ints apart

#define FID_PREV   11
#define FID_CLAIM  12

#define NROLE 11
#define SPIN_CAP (1 << 16)

// ====== tagged 64-bit mailbox protocol (XCD-0 pinned), r14 transport ======
// Transport verdict across r13..r17: ~1.7us/hop is transport-invariant
// (device coherence point). r18/r19 attack HOP COUNT (7->4) and keep every
// critical-path thread at <=320 persistent floats (r5 proved >400 spills
// hot weights and ~4x's the compute).
// r19 FIX vs r18: B must NOT write hist for layer 9 (row 8 is OOB — it
// clobbered x5mb/zmb/ctr and poisoned every tag; layer 9's past is always
// 0 since dil=512>=T, so the row is never read).
// Slot=(tag<<32)|payload in one 8B word; push = relaxed agent store; poll =
// relaxed agent load with every-16th returning-atomic fallback. Poison
// (0xAA..) reads as negative tag.
__device__ __forceinline__ void push_tag(u64* p, float v, int tag) {
  u64 pk = ((u64)(unsigned)tag << 32) | (unsigned)__float_as_int(v);
  __hip_atomic_store(p, pk, __ATOMIC_RELAXED, __HIP_MEMORY_SCOPE_AGENT);
}
__device__ __forceinline__ u64 atomic_slot(u64* p) {
  u64 r;
  asm volatile("global_atomic_add_x2 %0, %1, %2, off sc0\n\ts_waitcnt vmcnt(0)"
               : "=&v"(r) : "v"(p), "v"(0ULL) : "memory");
  return r;
}
__device__ __forceinline__ float poll_tag(u64* p, int want) {
  u64 r; int n = 0;
  for (;;) {
    r = ((n & 15) == 15)
            ? atomic_slot(p)
            : __hip_atomic_load(p, __ATOMIC_RELAXED, __HIP_MEMORY_SCOPE_AGENT);
    if ((int)(r >> 32) >= want) break;
    if (++n > SPIN_CAP) break;
  }
  return __int_as_float((int)(unsigned)(r & 0xffffffffULL));
}
__device__ __forceinline__ float2 poll_tag2(u64* p0, u64* p1, int want) {
  u64 r0, r1; int n = 0;
  for (;;) {
    if ((n & 15) == 15) {
      r0 = atomic_slot(p0);
      r1 = atomic_slot(p1);
    } else {
      r0 = __hip_atomic_load(p0, __ATOMIC_RELAXED, __HIP_MEMORY_SCOPE_AGENT);
      r1 = __hip_atomic_load(p1, __ATOMIC_RELAXED, __HIP_MEMORY_SCOPE_AGENT);
    }
    if ((int)(r0 >> 32) >= want && (int)(r1 >> 32) >= want) break;
    if (++n > SPIN_CAP) break;
  }
  return make_float2(__int_as_float((int)(unsigned)(r0 & 0xffffffffULL)),
                     __int_as_float((int)(unsigned)(r1 & 0xffffffffULL)));
}
__device__ __forceinline__ int flag_atomic(int* p) {
  int v;
  asm volatile("global_atomic_add %0, %1, %2, off sc0\n\ts_waitcnt vmcnt(0)"
               : "=&v"(v) : "v"(p), "v"(0) : "memory");
  return v;
}
__device__ __forceinline__ void push_flag(int* p, int v) {
  __hip_atomic_store(p, v, __ATOMIC_RELAXED, __HIP_MEMORY_SCOPE_AGENT);
}
__device__ __forceinline__ int wait_prev_wave(int* p, int want, int lane) {
  int v = 0, n = 0;
  do {
    if (lane == 0)
      v = ((n & 15) == 15)
              ? flag_atomic(p)
              : __hip_atomic_load(p, __ATOMIC_RELAXED, __HIP_MEMORY_SCOPE_AGENT);
    v = __shfl(v, 0, 64);
    if ((v >> 16) >= want) break;
  } while (++n <= SPIN_CAP);
  return v & 0xffff;
}

// ---- single-chain dot macros: EXACT r8/r13 arithmetic (absmax 0.0 proven).
#define DOTREG(N4, W, V4, ACC) do { \
  _Pragma("unroll") \
  for (int k_ = 0; k_ < (N4); ++k_) { float4 a_ = (V4)[k_]; \
    ACC = fmaf((W)[4*k_+0], a_.x, ACC); ACC = fmaf((W)[4*k_+1], a_.y, ACC); \
    ACC = fmaf((W)[4*k_+2], a_.z, ACC); ACC = fmaf((W)[4*k_+3], a_.w, ACC); } \
} while (0)

#define DOTREG_RELU(N4, W, V4, ACC) do { \
  _Pragma("unroll") \
  for (int k_ = 0; k_ < (N4); ++k_) { float4 a_ = (V4)[k_]; \
    a_.x = fmaxf(a_.x, 0.f); a_.y = fmaxf(a_.y, 0.f); \
    a_.z = fmaxf(a_.z, 0.f); a_.w = fmaxf(a_.w, 0.f); \
    ACC = fmaf((W)[4*k_+0], a_.x, ACC); ACC = fmaf((W)[4*k_+1], a_.y, ACC); \
    ACC = fmaf((W)[4*k_+2], a_.z, ACC); ACC = fmaf((W)[4*k_+3], a_.w, ACC); } \
} while (0)

__global__ void cond_prep_kernel(const float* __restrict__ condW,
                                 const float* __restrict__ y,
                                 float* __restrict__ cond8) {
  int idx = blockIdx.x * blockDim.x + threadIdx.x;
  if (idx >= FRAMES_ * L_ * G_) return;
  int f = idx / (L_ * G_);
  int row = idx - f * (L_ * G_);
  float acc = 0.f;
  for (int m = 0; m < MEL_; ++m)
    acc = fmaf(condW[row * MEL_ + m], y[m * FRAMES_ + f], acc);
  cond8[f * (L_ * G_) + row] = acc;
}

// LDS pool layout (byte offsets; branch-exclusive regions overlap)
#define EMB_B    0        // A: emb 64KB          | C: wo7T [64][256] 64KB
#define CONDW_B  65536    // A,B: cond 5*1024*4   | C: wolT [64][256] 64KB
#define BIASC_B  131072   // C: 10*256*4
#define XBUF_B   141312   // A,B: [6][64]*4
#define ZS_B     142848   // z_s[64]
#define Z9_B     143104   // z9_s[64]
#define VEC_B    143360   // vec_s[256]
#define LOG_B    144384   // logits_s[256]
#define POOL_SZ  145408

__global__ __launch_bounds__(256, 1) void wavenet_pipe(
    const float* __restrict__ samples,
    const int*   __restrict__ c_ptr,
    const float* __restrict__ emb,
    const float* __restrict__ WVp,
    const float* __restrict__ WVx,
    const float* __restrict__ Wo,
    const float* __restrict__ Wob,
    const float* __restrict__ Wol,
    const float* __restrict__ Wobl,
    const float* __restrict__ e1w,
    const float* __restrict__ e1b,
    const float* __restrict__ e2w,
    const float* __restrict__ e2b,
    float* __restrict__ ws,
    int*   __restrict__ out) {

  const int tid = threadIdx.x;

  float* cond8 = ws + COND8_OFF;
  float* hist  = ws + HIST_OFF;
  u64*   x5mb  = (u64*)(ws + MBX5_OFF);
  u64*   zmb   = (u64*)(ws + ZMB_OFF);
  u64*   ctr   = (u64*)(ws + CTR64_OFF);
  u64*   mbhid = (u64*)(ws + HID64_OFF);
  int*   flags = (int*)(ws + FLAG_OFF);
  int*   fprev = flags + FID_PREV * 16;

  __shared__ __align__(16) char pool_s[POOL_SZ];
  float* emb_s   = (float*)(pool_s + EMB_B);
  float* cond5_s = (float*)(pool_s + CONDW_B);
  float* wo7T_s  = (float*)(pool_s + EMB_B);     // C only
  float* wolT_s  = (float*)(pool_s + CONDW_B);   // C only
  float* biasC_s = (float*)(pool_s + BIASC_B);
  float (*xbuf_s)[R_] = (float(*)[R_])(pool_s + XBUF_B);
  float* z_s     = (float*)(pool_s + ZS_B);
  float* z9_s    = (float*)(pool_s + Z9_B);
  float* vec_s   = (float*)(pool_s + VEC_B);
  float* logits_s= (float*)(pool_s + LOG_B);
  __shared__ float wred[4], wsum[4];
  __shared__ int wcand[4];
  __shared__ int role_s;

  // ---- XCD-pinned role claiming (r7-proven) ----
  {
    unsigned xcc;
    asm volatile("s_getreg_b32 %0, hwreg(HW_REG_XCC_ID)" : "=s"(xcc));
    if (tid == 0) {
      int r = -1;
      if (xcc == 0) {
        int c0 = atomicAdd(flags + FID_CLAIM * 16, 1);
        if (c0 < NROLE) r = c0;
      }
      role_s = r;
    }
    __syncthreads();
  }
  const int bid = role_s;
  if (bid < 0) return;

  if (bid <= 1) {
    // ============ A (bid 0): layers 0-4 | B (bid 1): layers 5-9 ============
    // Critical-path-only residual chain: gates (tid<128, 5x64=320 regs,
    // r14-proven level), resid split so no thread exceeds 256.
    const int base = (bid == 0) ? 0 : 5;
    const int gr = tid >> 1, gh = tid & 1;

    float wxw[5][32], wxf[5][32];   // gate threads
    float wor[4][64], br[4];        // tid128..191: resid (A: l0-3, B: l5-8)
    float wox[64];  float bx = 0.f; // tid192..255: A: l4 resid | B: l8 skip x4
    float wsk1[64], wsk2[64], wsk3[64];  // B skip extra rows (3 more)
    if (tid < 128) {
      #pragma unroll
      for (int jl = 0; jl < 5; ++jl) {
        const float4* p = (const float4*)(WVx + ((size_t)((base + jl) * G_ + gr)) * R_ + gh * 32);
        #pragma unroll
        for (int i = 0; i < 8; ++i) ((float4*)wxw[jl])[i] = p[i];
        p = (const float4*)(WVx + ((size_t)((base + jl) * G_ + gr + 64)) * R_ + gh * 32);
        #pragma unroll
        for (int i = 0; i < 8; ++i) ((float4*)wxf[jl])[i] = p[i];
      }
    } else if (tid < 192) {
      const int r = tid - 128;
      #pragma unroll
      for (int jl = 0; jl < 4; ++jl) {
        const float* q = Wo + ((size_t)((base + jl) * (R_ + S_) + r)) * R_;
        #pragma unroll
        for (int i = 0; i < 64; ++i) wor[jl][i] = q[i];
        br[jl] = Wob[(base + jl) * (R_ + S_) + r];
      }
    } else {
      const int r = tid - 192;
      if (bid == 0) {
        const float* q = Wo + ((size_t)(4 * (R_ + S_) + r)) * R_;
        #pragma unroll
        for (int i = 0; i < 64; ++i) wox[i] = q[i];
        bx = Wob[4 * (R_ + S_) + r];
      } else {
        // l8 skip rows 64 + 4r .. 64 + 4r+3
        const float* q = Wo + ((size_t)(8 * (R_ + S_) + 64 + 4 * r)) * R_;
        #pragma unroll
        for (int i = 0; i < 64; ++i) wox[i]  = q[i];
        q += R_;
        #pragma unroll
        for (int i = 0; i < 64; ++i) wsk1[i] = q[i];
        q += R_;
        #pragma unroll
        for (int i = 0; i < 64; ++i) wsk2[i] = q[i];
        q += R_;
        #pragma unroll
        for (int i = 0; i < 64; ++i) wsk3[i] = q[i];
      }
    }
    for (int jl = 0; jl < 5; ++jl)
      for (int i = tid; i < FRAMES_ * G_; i += 256)
        cond5_s[jl * 1024 + i] = cond8[(i >> 7) * (L_ * G_) + (base + jl) * G_ + (i & 127)];
    if (bid == 0) {
      for (int i = tid; i < NCLS_ * R_ / 4; i += 256)
        ((float4*)emb_s)[i] = ((const float4*)emb)[i];
    }
    __syncthreads();
    float pdw[5], pdf[5];
    if (tid < 128 && gh == 0) {
      #pragma unroll
      for (int jl = 0; jl < 5; ++jl) {
        pdw[jl] = cond5_s[jl * 1024 + gr];
        pdf[jl] = cond5_s[jl * 1024 + gr + 64];
      }
    }

    for (int t = 0; t < T_; ++t) {
      // acquire x
      if (tid < 64) {
        if (bid == 0) {
          int prev = 127;
          if (t > 0) prev = wait_prev_wave(fprev, t, tid);
          if (tid < 16)
            ((float4*)xbuf_s[0])[tid] = ((const float4*)(emb_s + (size_t)prev * R_))[tid];
        } else {
          xbuf_s[0][tid] = poll_tag(x5mb + tid, t + 1);
        }
      }
      __syncthreads();

      #pragma unroll
      for (int jl = 0; jl < 5; ++jl) {
        const int jg = base + jl;
        // ---- gate (r9-exact) + immediate z publish ----
        if (tid < 128) {
          const float4* xs4 = (const float4*)(xbuf_s[jl] + gh * 32);
          float vw = 0.f, vf = 0.f;
          DOTREG(8, wxw[jl], xs4, vw);
          DOTREG(8, wxf[jl], xs4, vf);
          vw += __shfl_down(vw, 1, 2);
          vf += __shfl_down(vf, 1, 2);
          if (gh == 0) {
            float hw = vw + pdw[jl], hf = vf + pdf[jl];
            float zv = tanhf(hw) * (1.f / (1.f + expf(-hf)));
            z_s[gr] = zv;
            if (jg <= 6) push_tag(zmb + jg * 64 + gr, zv, t + 1);        // -> S_jg
            else if (jg == 7 || jg == 9) push_tag(zmb + jg * 64 + gr, zv, t + 1); // -> C
            // jg==8: local only (skip8 computed in this block)
          }
        } else if (tid >= 192) {
          // hist write: input of layer jg (= xbuf[jl]) -> hist row jg-1.
          // r19 FIX: jg==9 excluded — row 8 is OOB (l9 past always 0).
          if ((bid == 0 && jl >= 1) || (bid == 1 && jl <= 3))
            hist[(size_t)(jg - 1) * T_ * R_ + (size_t)t * R_ + (tid - 192)] = xbuf_s[jl][tid - 192];
        }
        __syncthreads();  // z ready

        // ---- resid / skip ----
        if (jl < 4) {
          if (tid >= 128 && tid < 192) {
            const int r = tid - 128;
            float v = 0.f;
            DOTREG(16, wor[jl], (const float4*)z_s, v);
            xbuf_s[jl + 1][r] = xbuf_s[jl][r] + v + br[jl];
          }
          if (bid == 1 && jl == 3 && tid >= 192) {
            // contrib8 (z8 ready): 4 rows/thread, exact row dots
            const int r = tid - 192;
            float v0 = 0.f, v1 = 0.f, v2 = 0.f, v3 = 0.f;
            DOTREG(16, wox,  (const float4*)z_s, v0);
            DOTREG(16, wsk1, (const float4*)z_s, v1);
            DOTREG(16, wsk2, (const float4*)z_s, v2);
            DOTREG(16, wsk3, (const float4*)z_s, v3);
            push_tag(ctr + 8 * 256 + 4 * r + 0, v0, t + 1);
            push_tag(ctr + 8 * 256 + 4 * r + 1, v1, t + 1);
            push_tag(ctr + 8 * 256 + 4 * r + 2, v2, t + 1);
            push_tag(ctr + 8 * 256 + 4 * r + 3, v3, t + 1);
          }
          __syncthreads();  // xbuf[jl+1] ready
        } else if (bid == 0) {
          // l4 resid -> CRITICAL push to B (producing thread pushes directly)
          if (tid >= 192) {
            const int r = tid - 192;
            float v = 0.f;
            DOTREG(16, wox, (const float4*)z_s, v);
            push_tag(x5mb + r, xbuf_s[4][r] + v + bx, t + 1);
          }
        }
        // bid==1, jl==4 (l9): gate already pushed z9; no resid.
      }

      // ---- pd precompute for t+1 (off critical path) ----
      const int tn = t + 1;
      if (tn < T_ && tid < 128) {
        const int f1 = tn >> 6;
        float wpw[32], wpf[32], pa[32];
        #pragma unroll
        for (int jl = 0; jl < 5; ++jl) {
          const int jg = base + jl;
          if (jg == 9) {
            if (gh == 0) {   // l9: past always 0 (dil=512)
              pdw[4] = cond5_s[4 * 1024 + f1 * G_ + gr];
              pdf[4] = cond5_s[4 * 1024 + f1 * G_ + gr + 64];
            }
            continue;
          }
          const float4* pw = (const float4*)(WVp + ((size_t)(jg * G_ + gr)) * R_ + gh * 32);
          const float4* pf = (const float4*)(WVp + ((size_t)(jg * G_ + gr + 64)) * R_ + gh * 32);
          #pragma unroll
          for (int i = 0; i < 8; ++i) { ((float4*)wpw)[i] = pw[i]; ((float4*)wpf)[i] = pf[i]; }
          if (jg == 0) {
            #pragma unroll
            for (int i = 0; i < 8; ++i) ((float4*)pa)[i] = ((const float4*)(xbuf_s[0] + gh * 32))[i];
          } else {
            const int tp = tn - (1 << jg);
            if (tp >= 0) {
              const float4* hp = (const float4*)(hist + (size_t)(jg - 1) * T_ * R_ + (size_t)tp * R_ + gh * 32);
              #pragma unroll
              for (int i = 0; i < 8; ++i) ((float4*)pa)[i] = hp[i];
            } else {
              #pragma unroll
              for (int i = 0; i < 32; ++i) pa[i] = 0.f;
            }
          }
          float vw = 0.f, vf = 0.f;
          const float4* pa4 = (const float4*)pa;
          DOTREG(8, wpw, pa4, vw);
          DOTREG(8, wpf, pa4, vf);
          vw += __shfl_down(vw, 1, 2);
          vf += __shfl_down(vf, 1, 2);
          if (gh == 0) {
            pdw[jl] = vw + cond5_s[jl * 1024 + f1 * G_ + gr];
            pdf[jl] = vf + cond5_s[jl * 1024 + f1 * G_ + gr + 64];
          }
        }
      }
      __syncthreads();  // end-of-step reuse guard
    }

  } else if (bid == 2) {
    // ============ C: fold + E1; v7/v9 from LDS-transposed weights ============
    const int o_loc = tid >> 1, halfc = tid & 1;
    float w0[128], w1[128];   // e1 halves: 256 regs, ZERO spill
    {
      const float* p = e1w + ((size_t)o_loc) * S_ + halfc * 128;
      #pragma unroll
      for (int i = 0; i < 128; ++i) w0[i] = p[i];
      p = e1w + ((size_t)(128 + o_loc)) * S_ + halfc * 128;
      #pragma unroll
      for (int i = 0; i < 128; ++i) w1[i] = p[i];
    }
    const float bias0 = e1b[o_loc], bias1 = e1b[128 + o_loc];
    for (int i = tid; i < 10 * S_; i += 256) {
      int j = i >> 8, s = i & 255;
      biasC_s[i] = (j < 9) ? Wob[j * (R_ + S_) + 64 + s] : Wobl[s];
    }
    // transposed [k][s] layouts: conflict-free LDS reads, exact k-order dots
    for (int k = 0; k < 64; ++k) {
      wo7T_s[k * 256 + tid] = Wo[((size_t)(7 * (R_ + S_) + 64 + tid)) * R_ + k];
      wolT_s[k * 256 + tid] = Wol[(size_t)tid * R_ + k];
    }
    __syncthreads();

    for (int t = 0; t < T_; ++t) {
      if (tid < 64)       z_s[tid]       = poll_tag(zmb + 7 * 64 + tid, t + 1);
      else if (tid < 128) z9_s[tid - 64] = poll_tag(zmb + 9 * 64 + (tid - 64), t + 1);
      __syncthreads();
      // v7/v9: exact k-ascending single-acc chains (== DOTREG order)
      float v7 = 0.f, v9 = 0.f;
      #pragma unroll
      for (int k = 0; k < 64; ++k) {
        v7 = fmaf(wo7T_s[k * 256 + tid], z_s[k],  v7);
        v9 = fmaf(wolT_s[k * 256 + tid], z9_s[k], v9);
      }
      // ordered fold j=0..9 (r13-exact: s=(s+v_j)+b_j)
      float sacc = 0.f;
      for (int kk = 0; kk < 3; ++kk) {
        float2 v = poll_tag2(ctr + (size_t)(2 * kk) * S_ + tid,
                             ctr + (size_t)(2 * kk + 1) * S_ + tid, t + 1);
        sacc = (sacc + v.x) + biasC_s[(2 * kk) * S_ + tid];
        sacc = (sacc + v.y) + biasC_s[(2 * kk + 1) * S_ + tid];
      }
      float v6 = poll_tag(ctr + 6 * 256 + tid, t + 1);
      sacc = (sacc + v6) + biasC_s[6 * 256 + tid];
      sacc = (sacc + v7) + biasC_s[7 * 256 + tid];
      float v8 = poll_tag(ctr + 8 * 256 + tid, t + 1);
      sacc = (sacc + v8) + biasC_s[8 * 256 + tid];
      sacc = (sacc + v9) + biasC_s[9 * 256 + tid];
      vec_s[tid] = sacc;
      __syncthreads();
      const float4* s4 = (const float4*)(vec_s + halfc * 128);
      float v0 = 0.f, v1 = 0.f;
      DOTREG_RELU(32, w0, s4, v0);
      v0 += __shfl_down(v0, 1, 2);
      DOTREG_RELU(32, w1, s4, v1);
      v1 += __shfl_down(v1, 1, 2);
      if (halfc == 0) {
        push_tag(mbhid + o_loc,       fmaxf(v0 + bias0, 0.f), t + 1);
        push_tag(mbhid + 128 + o_loc, fmaxf(v1 + bias1, 0.f), t + 1);
      }
      __syncthreads();  // vec_s/z_s reuse guard
    }

  } else if (bid == 3) {
    // ============ D: E2 + sampling (r8-exact) ============
    const int o_loc = tid >> 1, halfc = tid & 1;
    const float cf = (float)c_ptr[0];
    float w0[128], w1[128];
    {
      const float* p = e2w + ((size_t)o_loc) * END_ + halfc * 128;
      #pragma unroll
      for (int i = 0; i < 128; ++i) w0[i] = p[i];
      p = e2w + ((size_t)(128 + o_loc)) * END_ + halfc * 128;
      #pragma unroll
      for (int i = 0; i < 128; ++i) w1[i] = p[i];
    }
    const float bias0 = e2b[o_loc], bias1 = e2b[128 + o_loc];
    const int lane = tid & 63, wv = tid >> 6;

    for (int t = 0; t < T_; ++t) {
      vec_s[tid] = poll_tag(mbhid + tid, t + 1);
      __syncthreads();
      const float4* h4 = (const float4*)(vec_s + halfc * 128);
      float v0 = 0.f, v1 = 0.f;
      DOTREG(32, w0, h4, v0);
      v0 += __shfl_down(v0, 1, 2);
      DOTREG(32, w1, h4, v1);
      v1 += __shfl_down(v1, 1, 2);
      if (halfc == 0) {
        logits_s[o_loc]       = (v0 + bias0) * cf;
        logits_s[128 + o_loc] = (v1 + bias1) * cf;
      }
      __syncthreads();

      // ---- softmax-CDF sampling over 256 logits (r8 verbatim) ----
      float lg = logits_s[tid];
      float m = lg;
      #pragma unroll
      for (int off = 32; off >= 1; off >>= 1) m = fmaxf(m, __shfl_xor(m, off, 64));
      if (lane == 0) wred[wv] = m;
      __syncthreads();
      m = fmaxf(fmaxf(wred[0], wred[1]), fmaxf(wred[2], wred[3]));
      float e = expf(lg - m);
      float cs = e;
      #pragma unroll
      for (int off = 1; off < 64; off <<= 1) {
        float o_ = __shfl_up(cs, off, 64);
        if (lane >= off) cs += o_;
      }
      if (lane == 63) wsum[wv] = cs;
      __syncthreads();
      float total = wsum[0] + wsum[1] + wsum[2] + wsum[3];
      float offv = 0.f;
      for (int w2 = 0; w2 < wv; ++w2) offv += wsum[w2];
      float thresh = samples[t] * total;
      bool flagb = (offv + cs) > thresh;
      unsigned long long mk = __ballot(flagb);
      if (lane == 0) wcand[wv] = mk ? (wv * 64 + __ffsll(mk) - 1) : 100000;
      __syncthreads();
      if (tid == 0) {
        int nw = min(min(wcand[0], wcand[1]), min(wcand[2], wcand[3]));
        if (nw >= 100000) nw = 0;  // argmax of all-False -> 0
        out[t] = nw;
        push_flag(fprev, ((t + 1) << 16) | nw);
      }
      __syncthreads();  // protect wred/wsum/logits_s before next step
    }

  } else {
    // ============ S_j (bid 4..10): skip contribs for layer j = bid-4 ============
    const int j = bid - 4;
    float wsk[64];
    {
      const float* q = Wo + ((size_t)(j * (R_ + S_) + 64 + tid)) * R_;
      #pragma unroll
      for (int i = 0; i < 64; ++i) wsk[i] = q[i];
    }
    u64* zin  = zmb + j * 64;
    u64* cout = ctr + (size_t)j * 256;
    for (int t = 0; t < T_; ++t) {
      if (tid < 64) z_s[tid] = poll_tag(zin + tid, t + 1);
      __syncthreads();
      float v = 0.f;
      DOTREG(16, wsk, (const float4*)z_s, v);
      push_tag(cout + tid, v, t + 1);
      __syncthreads();  // z_s reuse guard
    }
  }
}

extern "C" void kernel_launch(void* const* d_in, const int* in_sizes, int n_in,
                              void* d_out, int out_size, void* d_ws, size_t ws_size,
                              hipStream_t stream) {
  const float* y       = (const float*)d_in[0];
  const float* samples = (const float*)d_in[1];
  const int*   c       = (const int*)d_in[2];
  const float* emb     = (const float*)d_in[3];
  const float* condW   = (const float*)d_in[4];
  const float* WVp     = (const float*)d_in[5];
  const float* WVx     = (const float*)d_in[6];
  const float* Wo      = (const float*)d_in[7];
  const float* Wob     = (const float*)d_in[8];
  const float* Wol     = (const float*)d_in[9];
  const float* Wobl    = (const float*)d_in[10];
  const float* e1w     = (const float*)d_in[11];
  const float* e1b     = (const float*)d_in[12];
  const float* e2w     = (const float*)d_in[13];
  const float* e2b     = (const float*)d_in[14];

  float* ws  = (float*)d_ws;
  int*   out = (int*)d_out;

  // Only flags need zeroing; mailbox tags rely on the 0xAA poison reading as
  // negative (never >= any t+1). Harness re-poisons ws before every launch.
  hipMemsetAsync((char*)d_ws + (size_t)FLAG_OFF * sizeof(float), 0,
                 16 * 16 * sizeof(int), stream);

  cond_prep_kernel<<<(FRAMES_ * L_ * G_ + 255) / 256, 256, 0, stream>>>(
      condW, y, ws + COND8_OFF);

  wavenet_pipe<<<256, 256, 0, stream>>>(samples, c, emb, WVp, WVx, Wo, Wob,
                                        Wol, Wobl, e1w, e1b, e2w, e2b, ws, out);
}